// Round 12
// baseline (139.194 us; speedup 1.0000x reference)
//
#include <hip/hip_runtime.h>
#include <stdint.h>

#define BATCH 32
#define HDIM 224
#define WDIM 224
#define CDIM 3
#define KTOT (HDIM * WDIM * CDIM)   // 150528
#define HID 64
#define KCHUNK 64
#define NBLK1 (KTOT / KCHUNK)       // 2352
#define PIX (HDIM * WDIM)           // 50176
#define BLK3 49                      // blocks per batch: 1024 thr * 1 px
#define NBLK3 (BATCH * BLK3)         // 1568

#define NSHARD 16
#define BH (BATCH * HID)             // 2048
#define HACC_BYTES (NSHARD * BH * 4) // 128 KB
#define PART_BYTES ((size_t)NBLK1 * BH * 4)  // 19.3 MB

typedef float float4v __attribute__((ext_vector_type(4)));
// 4-byte-aligned vector loads (texel addresses are only 4B aligned)
typedef float float4u __attribute__((ext_vector_type(4), aligned(4)));
typedef float float2u __attribute__((ext_vector_type(2), aligned(4)));

// ---------------- Kernel 1: part[blk] = flat @ w1 slice (split-K) -----------
// r7 form VERBATIM (best measured total, 131.0us). ATTRIBUTION ROUND: k1/k2
// frozen; only k3's grid is doubled to force its counters above the 41us
// fill-row cutoff (k3 has never appeared in top-5 across 12 rounds; its
// ~38us ledger estimate is inference, never measurement).
__global__ __launch_bounds__(256, 6) void k1_gemm(const float* __restrict__ flat,
                                                  const float* __restrict__ w1,
                                                  float* __restrict__ hacc,
                                                  float* __restrict__ part) {
    __shared__ float smem[6144];                 // 24 KB
    const int tid  = threadIdx.x;
    const int lane = tid & 63;                   // hid
    const int wave = tid >> 6;
    const int k0   = blockIdx.x * KCHUNK;
    const int kw   = wave * 16;

    // --- Issue all 6 global_load_dwordx4 per thread (pipelined) ---
    float4v rf0, rf1, rw0, rw1, rw2, rw3;
    {
        const int f0 = tid, f1 = tid + 256;      // flat float4 idx 0..511
        rf0 = *(const float4v*)(flat + (size_t)(f0 >> 4) * KTOT + k0 + (f0 & 15) * 4);
        rf1 = *(const float4v*)(flat + (size_t)(f1 >> 4) * KTOT + k0 + (f1 & 15) * 4);
        const float* wbase = w1 + (size_t)k0 * HID;
        rw0 = *(const float4v*)(wbase + (size_t)(tid +   0) * 4);
        rw1 = *(const float4v*)(wbase + (size_t)(tid + 256) * 4);
        rw2 = *(const float4v*)(wbase + (size_t)(tid + 512) * 4);
        rw3 = *(const float4v*)(wbase + (size_t)(tid + 768) * 4);
    }
    // --- ds_write as results land (compiler emits counted vmcnt) ---
    *(float4v*)(smem + (size_t)tid * 4)         = rf0;
    *(float4v*)(smem + (size_t)(tid + 256) * 4) = rf1;
    *(float4v*)(smem + 2048 + (size_t)(tid +   0) * 4) = rw0;
    *(float4v*)(smem + 2048 + (size_t)(tid + 256) * 4) = rw1;
    *(float4v*)(smem + 2048 + (size_t)(tid + 512) * 4) = rw2;
    *(float4v*)(smem + 2048 + (size_t)(tid + 768) * 4) = rw3;
    __syncthreads();

    float acc[32];
#pragma unroll
    for (int j = 0; j < 32; ++j) acc[j] = 0.0f;

    // Per kk-iter: 4 b-invariant w-reads (stride-64-word -> 2-way = free)
    // + 32 broadcast ds_read_b128 + 128 FMAs.
#pragma unroll
    for (int kk = 0; kk < 16; kk += 4) {
        const float w0  = smem[2048 + (kw + kk + 0) * 64 + lane];
        const float w1v = smem[2048 + (kw + kk + 1) * 64 + lane];
        const float w2v = smem[2048 + (kw + kk + 2) * 64 + lane];
        const float w3v = smem[2048 + (kw + kk + 3) * 64 + lane];
#pragma unroll
        for (int b = 0; b < 32; ++b) {
            const float4v x = *(const float4v*)(smem + b * 64 + kw + kk);
            float a = acc[b];
            a = fmaf(x.x, w0, a);
            a = fmaf(x.y, w1v, a);
            a = fmaf(x.z, w2v, a);
            a = fmaf(x.w, w3v, a);
            acc[b] = a;
        }
    }
    __syncthreads();                             // LDS tiles fully consumed

    // --- Waves 1..3 dump partials (24 KB); wave 0 reduces + stores ---
    if (wave) {
#pragma unroll
        for (int j = 0; j < 32; ++j)
            smem[(wave - 1) * 2048 + j * 64 + lane] = acc[j];
    }
    __syncthreads();
    if (wave == 0) {
        if (part) {                              // 2-stage: streaming store
            float* po = part + (size_t)blockIdx.x * BH;
#pragma unroll
            for (int j = 0; j < 32; ++j) {
                const int idx = j * 64 + lane;
                po[idx] = acc[j] + smem[idx] + smem[2048 + idx] + smem[4096 + idx];
            }
        } else {                                 // fallback: sharded atomics
            float* ha = hacc + (blockIdx.x & (NSHARD - 1)) * BH;
#pragma unroll
            for (int j = 0; j < 32; ++j) {
                const int idx = j * 64 + lane;
                atomicAdd(ha + idx,
                          acc[j] + smem[idx] + smem[2048 + idx] + smem[4096 + idx]);
            }
        }
    }
}

// -------- Kernel 2 (2-stage mode): reduce 2352 partials -> 16 shards --------
// r7 form VERBATIM: 512 blocks (2/CU), each owns shard slot hacc[q][b][*]
// (q<16, 147 rows each). Zero atomics, zero memset. k3 sums the 16 shards.
__global__ __launch_bounds__(256) void k2_reduce(const float* __restrict__ part,
                                                 float* __restrict__ hacc) {
    const int b    = blockIdx.x >> 4;            // 0..31
    const int q    = blockIdx.x & 15;            // 0..15
    const int tid  = threadIdx.x;
    const int lane = tid & 63;
    const int wave = tid >> 6;
    const int r0   = q * 147;

    float s = 0.0f;
    for (int r = r0 + wave; r < r0 + 147; r += 4)
        s += part[(size_t)r * BH + b * HID + lane];

    __shared__ float red[3][64];
    if (wave) red[wave - 1][lane] = s;
    __syncthreads();
    if (wave == 0)
        hacc[q * BH + b * HID + lane] =
            s + red[0][lane] + red[1][lane] + red[2][lane];
}

// -------- Kernel 3: head + affine grid + bilinear sampling ------------------
// r7 body; ATTRIBUTION: grid doubled. Blocks >= NBLK3 redo blocks 0..NBLK3-1
// verbatim -- theta is recomputed identically from the same finished hacc,
// so both copies store byte-identical values to the same addresses (benign).
// Compiler cannot eliminate either copy (separate blocks). The k3 dispatch
// dur ~2x single-cost > 41us fill rows -> its counters surface in top-5.
__global__ __launch_bounds__(1024) void k3_sample(const float* __restrict__ img,
                                                  const float* __restrict__ hacc,
                                                  const float* __restrict__ b1,
                                                  const float* __restrict__ w2,
                                                  const float* __restrict__ b2,
                                                  float* __restrict__ out) {
    int vb = blockIdx.x;
    if (vb >= NBLK3) vb -= NBLK3;                // duplicate pass
    const int b     = vb / BLK3;
    const int strip = vb - b * BLK3;
    const int tid   = threadIdx.x;
    const int lane  = tid & 63;

    __shared__ float sth[6];
    if (tid < 64) {                              // wave 0: lane = hid
        float a = 0.0f;
#pragma unroll
        for (int s = 0; s < NSHARD; ++s)
            a += hacc[s * BH + b * HID + lane];
        const float hv = tanhf(a + b1[lane]);
        const float* w2p = w2 + lane * 6;        // w2 is [HID][6] row-major
        float q[6];
#pragma unroll
        for (int t = 0; t < 6; ++t) q[t] = hv * w2p[t];
#pragma unroll
        for (int off = 32; off >= 1; off >>= 1) {
#pragma unroll
            for (int t = 0; t < 6; ++t) q[t] += __shfl_xor(q[t], off);
        }
        if (lane < 6) sth[lane] = tanhf(q[lane] + b2[lane]);
    }
    __syncthreads();

    const float t0 = sth[0], t1 = sth[1], t2 = sth[2];
    const float t3 = sth[3], t4 = sth[4], t5 = sth[5];

    const float* base = img + (size_t)b * KTOT;
    const int pix = strip * 1024 + tid;
    const int i   = pix / WDIM;
    const int j   = pix - i * WDIM;

    const float xt = (2.0f * (float)j - (float)(WDIM - 1)) / (float)(WDIM - 1);
    const float yt = (2.0f * (float)i - (float)(HDIM - 1)) / (float)(HDIM - 1);

    const float xs = t0 * xt + t1 * yt + t2;
    const float ys = t3 * xt + t4 * yt + t5;

    const float x = 0.5f * (xs + 1.0f) * (float)(WDIM - 1);
    const float y = 0.5f * (ys + 1.0f) * (float)(HDIM - 1);

    const int x0 = (int)floorf(x);
    const int y0 = (int)floorf(y);

    const int x0c = min(max(x0, 0), WDIM - 1);
    const int x1c = min(max(x0 + 1, 0), WDIM - 1);
    const int y0c = min(max(y0, 0), HDIM - 1);
    const int y1c = min(max(y0 + 1, 0), HDIM - 1);

    // Reference computes weights from CLIPPED corner coordinates.
    const float x0f = (float)x0c, x1f = (float)x1c;
    const float y0f = (float)y0c, y1f = (float)y1c;

    const float wa = (x1f - x) * (y1f - y);
    const float wb = (x1f - x) * (y - y0f);
    const float wc = (x - x0f) * (y1f - y);
    const float wd = (x - x0f) * (y - y0f);

    // Both corners of a row are adjacent texels (x1c == x0c+1 whenever the
    // clamp doesn't bind); fetch each row as one 16B + one 8B load. min()
    // keeps the tail access in-bounds.
    int oA = (y0c * WDIM + x0c) * 3;
    int oB = (y1c * WDIM + x0c) * 3;
    oA = min(oA, KTOT - 6);
    oB = min(oB, KTOT - 6);
    const float4u Ar  = *(const float4u*)(base + oA);      // a0 a1 a2 c0
    const float2u Ar2 = *(const float2u*)(base + oA + 4);  // c1 c2
    const float4u Br  = *(const float4u*)(base + oB);      // b0 b1 b2 d0
    const float2u Br2 = *(const float2u*)(base + oB + 4);  // d1 d2

    const float r0 = wa * Ar.x + wb * Br.x + wc * Ar.w  + wd * Br.w;
    const float r1 = wa * Ar.y + wb * Br.y + wc * Ar2.x + wd * Br2.x;
    const float r2 = wa * Ar.z + wb * Br.z + wc * Ar2.y + wd * Br2.y;

    float* po = out + (size_t)b * KTOT + (size_t)pix * 3;
    float2u rv; rv.x = r0; rv.y = r1;
    *(float2u*)po = rv;
    po[2] = r2;
}

extern "C" void kernel_launch(void* const* d_in, const int* in_sizes, int n_in,
                              void* d_out, int out_size, void* d_ws, size_t ws_size,
                              hipStream_t stream) {
    const float* inputs = (const float*)d_in[0];
    const float* w1     = (const float*)d_in[1];
    const float* b1     = (const float*)d_in[2];
    const float* w2     = (const float*)d_in[3];
    const float* b2     = (const float*)d_in[4];
    float* out = (float*)d_out;

    float* hacc = (float*)d_ws;                  // NSHARD * 2048 floats
    float* part = (float*)((char*)d_ws + HACC_BYTES);
    const bool two_stage = ws_size >= HACC_BYTES + PART_BYTES;

    if (two_stage) {
        // k2 writes all 16 shards -> no memset, no atomics anywhere.
        k1_gemm<<<NBLK1, 256, 0, stream>>>(inputs, w1, hacc, part);
        k2_reduce<<<512, 256, 0, stream>>>(part, hacc);
    } else {
        hipMemsetAsync(hacc, 0, HACC_BYTES, stream);
        k1_gemm<<<NBLK1, 256, 0, stream>>>(inputs, w1, hacc, (float*)nullptr);
    }
    // ATTRIBUTION: doubled grid (second half duplicates first half's work
    // and writes identical values) -- surfaces k3's counters above the fill.
    k3_sample<<<2 * NBLK3, 1024, 0, stream>>>(inputs, hacc, b1, w2, b2, out);
}